// Round 1
// baseline (306.548 us; speedup 1.0000x reference)
//
#include <hip/hip_runtime.h>

// Problem constants
#define MDIM 8192
#define IDIM 1024
#define ODIM 1024
#define D1   9            // DEGREE+1
#define KDIM (IDIM * D1)  // 9216, k = d*1024 + i ordering

typedef _Float16 half8 __attribute__((ext_vector_type(8)));
typedef float    float4v __attribute__((ext_vector_type(4)));

#define BSCALE 256.0f     // pre-scale B into f16-normal range (exact pow2)
#define INV_BSCALE (1.0f / 256.0f)

// ---------------------------------------------------------------------------
// Hermite-function basis for one squashed input value.
// ---------------------------------------------------------------------------
__device__ __forceinline__ void hermite9(float xv, float h[D1]) {
    float ax = fabsf(xv);
    float t  = __expf(-2.0f * ax);
    float th = (1.0f - t) / (1.0f + t);      // tanh(|x|)
    th = copysignf(th, xv);
    float u = th * 5.123105625617661f;       // sqrt(17) + 1
    float g = __expf(-0.5f * u * u);
    h[0] = 0.7511255444649425f * g;          // pi^-1/4 * gauss
    h[1] = 1.0622519497598084f * u * g;      // sqrt(2)*pi^-1/4 * u * gauss
    const float c1[D1] = {0.f, 0.f, 1.0f, 0.8164965809277260f, 0.7071067811865476f,
                          0.6324555320336759f, 0.5773502691896258f, 0.5345224838248488f, 0.5f};
    const float c2[D1] = {0.f, 0.f, 0.7071067811865476f, 0.8164965809277260f, 0.8660254037844386f,
                          0.8944271909999159f, 0.9128709291752769f, 0.9258200997725514f, 0.9354143466934853f};
#pragma unroll
    for (int d = 2; d < D1; ++d) h[d] = c1[d] * u * h[d - 1] - c2[d] * h[d - 2];
}

// ---------------------------------------------------------------------------
// prep_b: coeffs fp32 [I][O][9] -> Bt f16 [O][K], Bt[o][d*1024+i] = 256*C[i][o][d]
// One thread per (o,i), i fastest -> coalesced 2B writes per d.
// ---------------------------------------------------------------------------
__global__ void prep_b(const float* __restrict__ C, _Float16* __restrict__ Bt) {
    int t = blockIdx.x * 256 + threadIdx.x;   // 0 .. 1024*1024-1
    int o = t >> 10;
    int i = t & 1023;
    const float* cp = C + ((size_t)i * ODIM + o) * D1;
    _Float16* bp = Bt + (size_t)o * KDIM + i;
#pragma unroll
    for (int d = 0; d < D1; ++d)
        bp[(size_t)d * IDIM] = (_Float16)(cp[d] * BSCALE);
}

// ---------------------------------------------------------------------------
// prep_h: x fp32 [8192][1024] -> H f16 [nrows][K], H[r][d*1024+i] = h_d(x[row0+r][i])
// One thread per 8 consecutive i; half8 (16B) stores, fully coalesced.
// ---------------------------------------------------------------------------
__global__ void prep_h(const float* __restrict__ x, _Float16* __restrict__ H,
                       int row0, int nrows) {
    int t = blockIdx.x * 256 + threadIdx.x;
    int r = t >> 7;                 // chunk-local row (128 threads per row)
    int ig = (t & 127) << 3;        // i0
    if (r >= nrows) return;
    const float* xp = x + ((size_t)(row0 + r) << 10) + ig;
    float4 a0 = *(const float4*)xp;
    float4 a1 = *(const float4*)(xp + 4);
    float xv[8] = {a0.x, a0.y, a0.z, a0.w, a1.x, a1.y, a1.z, a1.w};
    float h[8][D1];
#pragma unroll
    for (int e = 0; e < 8; ++e) hermite9(xv[e], h[e]);
    _Float16* hp = H + (size_t)r * KDIM + ig;
#pragma unroll
    for (int d = 0; d < D1; ++d) {
        half8 v;
#pragma unroll
        for (int e = 0; e < 8; ++e) v[e] = (_Float16)h[e][d];
        *(half8*)(hp + (size_t)d * IDIM) = v;
    }
}

// ---------------------------------------------------------------------------
// gemm_hf: C[m][n] += A[m][k] * Bt[n][k], f16 MFMA 16x16x32, fp32 accum.
// 128x128 block tile, 256 threads (4 waves, 2x2), BK=64,
// global_load_lds dwordx4 staging with XOR k-group swizzle (bank-conflict-free
// ds_read_b128 fragment reads: 8-way quad spread, 2-way lane alias = free).
// ---------------------------------------------------------------------------
__global__ __launch_bounds__(256, 2) void gemm_hf(
    const _Float16* __restrict__ A,    // [rows][KDIM]
    const _Float16* __restrict__ Bt,   // [ODIM][KDIM]
    float* __restrict__ out)           // [rows][ODIM]
{
    const int tid = threadIdx.x;
    const int w = tid >> 6;       // wave 0..3
    const int l = tid & 63;       // lane
    const int bn = blockIdx.x;    // n-tile 0..7  (fast dim -> per-XCD B-panel L2 reuse)
    const int bm = blockIdx.y;    // m-tile

    __shared__ _Float16 As[128 * 64];
    __shared__ _Float16 Bs[128 * 64];

    // --- staging assignment: lane l, rep r loads 16B into LDS slot (row, l&7)
    // row = (r*4+w)*8 + l/8 ; stored data is global k-group (l&7)^(l/8)  (XOR swizzle)
    const int lrow8 = l >> 3;
    const int kgrp  = (l & 7) ^ lrow8;
    const _Float16* Ag = A  + ((size_t)(bm * 128 + w * 8 + lrow8) * KDIM + kgrp * 8);
    const _Float16* Bg = Bt + ((size_t)(bn * 128 + w * 8 + lrow8) * KDIM + kgrp * 8);

    // --- compute-side fragment indices
    const int q   = l >> 4;       // k-quad
    const int m16 = l & 15;
    const int s3  = m16 & 7;      // row&7 for swizzle un-mapping
    const int wm  = w >> 1, wn = w & 1;

    float4v acc[4][4] = {};

    for (int k0 = 0; k0 < KDIM; k0 += 64) {
#pragma unroll
        for (int r = 0; r < 4; ++r) {
            __builtin_amdgcn_global_load_lds(
                (const __attribute__((address_space(1))) void*)(Ag + (size_t)(r * 32) * KDIM + k0),
                (__attribute__((address_space(3))) void*)((char*)As + (r * 4 + w) * 1024),
                16, 0, 0);
            __builtin_amdgcn_global_load_lds(
                (const __attribute__((address_space(1))) void*)(Bg + (size_t)(r * 32) * KDIM + k0),
                (__attribute__((address_space(3))) void*)((char*)Bs + (r * 4 + w) * 1024),
                16, 0, 0);
        }
        __syncthreads();   // drains vmcnt, publishes LDS tiles

#pragma unroll
        for (int ko = 0; ko < 2; ++ko) {
            const int slot = (q + 4 * ko) ^ s3;   // swizzled k-group
            half8 af[4], bf[4];
#pragma unroll
            for (int i = 0; i < 4; ++i) {
                af[i] = *(const half8*)&As[(wm * 64 + i * 16 + m16) * 64 + slot * 8];
                bf[i] = *(const half8*)&Bs[(wn * 64 + i * 16 + m16) * 64 + slot * 8];
            }
#pragma unroll
            for (int i = 0; i < 4; ++i)
#pragma unroll
                for (int j = 0; j < 4; ++j)
                    acc[i][j] = __builtin_amdgcn_mfma_f32_16x16x32_f16(af[i], bf[j], acc[i][j], 0, 0, 0);
        }
        __syncthreads();   // tile consumed, safe to overwrite
    }

    // --- epilogue: D row = quad*4 + reg, col = lane&15 (verified m89 layout)
#pragma unroll
    for (int i = 0; i < 4; ++i) {
        int row = bm * 128 + wm * 64 + i * 16 + q * 4;
#pragma unroll
        for (int j = 0; j < 4; ++j) {
            int col = bn * 128 + wn * 64 + j * 16 + m16;
            float* op = out + (size_t)row * ODIM + col;
#pragma unroll
            for (int r2 = 0; r2 < 4; ++r2)
                op[(size_t)r2 * ODIM] = acc[i][j][r2] * INV_BSCALE;
        }
    }
}

// ---------------------------------------------------------------------------
// naive fallback (only if workspace is too small to hold Bt + one 128-row H)
// ---------------------------------------------------------------------------
__global__ void naive_kernel(const float* __restrict__ x, const float* __restrict__ C,
                             float* __restrict__ out) {
    __shared__ float hb[IDIM * D1];   // 36 KB
    int b = blockIdx.x;
    int tid = threadIdx.x;
    for (int i = tid; i < IDIM; i += 256) {
        float h[D1];
        hermite9(x[(size_t)b * IDIM + i], h);
#pragma unroll
        for (int d = 0; d < D1; ++d) hb[i * D1 + d] = h[d];
    }
    __syncthreads();
    for (int o = tid; o < ODIM; o += 256) {
        float acc = 0.f;
        for (int i = 0; i < IDIM; ++i) {
            const float* cp = C + ((size_t)i * ODIM + o) * D1;
            const float* hp = hb + i * D1;
#pragma unroll
            for (int d = 0; d < D1; ++d) acc += hp[d] * cp[d];
        }
        out[(size_t)b * ODIM + o] = acc;
    }
}

// ---------------------------------------------------------------------------
extern "C" void kernel_launch(void* const* d_in, const int* in_sizes, int n_in,
                              void* d_out, int out_size, void* d_ws, size_t ws_size,
                              hipStream_t stream) {
    const float* x      = (const float*)d_in[0];   // [8192][1024]
    const float* coeffs = (const float*)d_in[1];   // [1024][1024][9]
    float* out = (float*)d_out;                    // [8192][1024]

    const size_t bt_bytes = (size_t)ODIM * KDIM * sizeof(_Float16);  // 18.9 MB
    size_t avail = ws_size > bt_bytes ? ws_size - bt_bytes : 0;
    long rows = (long)(avail / ((size_t)KDIM * sizeof(_Float16)));
    rows = (rows / 128) * 128;
    if (rows > MDIM) rows = MDIM;

    if (rows >= 128) {
        _Float16* Bt = (_Float16*)d_ws;
        _Float16* H  = (_Float16*)((char*)d_ws + bt_bytes);
        hipLaunchKernelGGL(prep_b, dim3((IDIM * ODIM) / 256), dim3(256), 0, stream, coeffs, Bt);
        for (int row0 = 0; row0 < MDIM; row0 += (int)rows) {
            int nr = (MDIM - row0) < rows ? (MDIM - row0) : (int)rows;
            hipLaunchKernelGGL(prep_h, dim3(nr / 2), dim3(256), 0, stream, x, H, row0, nr);
            hipLaunchKernelGGL(gemm_hf, dim3(8, nr / 128), dim3(256), 0, stream,
                               H, Bt, out + (size_t)row0 * ODIM);
        }
    } else {
        hipLaunchKernelGGL(naive_kernel, dim3(MDIM), dim3(256), 0, stream, x, coeffs, out);
    }
}